// Round 5
// baseline (171.277 us; speedup 1.0000x reference)
//
#include <hip/hip_runtime.h>
#include <math.h>

// loss = ALPHA * mean(level_w * (softplus(x) - x*t))
//      + BETA  * sum_{b,e} relu(sig(x[b,dst]) - sig(x[b,src])) / (B*N)
//
// R10: two-kernel split at the phase boundary. Three rounds (R6/R8/R9,
// VGPR 52/52/60) proved hipcc always sinks register prefetch into the
// consumer -- the fused kernel executes phase-serialized at ~47 us no
// matter the schedule pins. Fix:
//  K1 sig_bce_kernel: pure streaming. sigmoid+BCE, P (fp16, tile-major
//     [B/4][N] h4 layout) -> 32 MB workspace. No LDS/barriers: runs at
//     memory pace by construction.
//  K2 edge_kernel: per block, stage 4 pre-computed 32 KB P tiles via
//     global_load_lds (linear dest = the legal pattern), double-buffered,
//     raw s_barrier with vmcnt-only waits (never drains mid-pipeline via
//     __syncthreads), gather edges from LDS. Copy-under-gather overlap is
//     DMA-enforced -- the compiler cannot sink it.
// P is produced once, consumed ~8x, all L3-resident (32 MB < 256 MB).
// Falls back to the proven R5 fused kernel if ws_size < 32 MB.

#define ALPHA_C 1.0f
#define BETA_C  0.5f

constexpr int B = 4096;
constexpr int N = 4096;
constexpr int E = 16384;
constexpr size_t PG_BYTES = (size_t)B * N * 2;   // 32 MB fp16 workspace

typedef _Float16 h4 __attribute__((ext_vector_type(4)));
typedef _Float16 h8 __attribute__((ext_vector_type(8)));

__global__ __launch_bounds__(64) void init_out_kernel(float* out) {
    if (threadIdx.x == 0) out[0] = 0.0f;
}

__device__ __forceinline__ void fast_sig_sp(float x, float& p, float& sp) {
    // q = exp(-|x|) in (0,1]; both sigmoid and softplus from one exp
    float q = __expf(-fabsf(x));
    float d = 1.0f + q;
    float r = __builtin_amdgcn_rcpf(d);     // ~1 ulp approx reciprocal
    p  = (x >= 0.0f) ? r : q * r;           // sigmoid
    sp = fmaxf(x, 0.0f) + __logf(d);        // softplus = max(x,0)+log(1+q)
}

// ---------------- K1: streaming sigmoid + BCE, P -> workspace ----------------
// 2048 blocks x 512 threads. tile = blk>>1 (4 rows), col half = blk&1.
// Thread handles nodes 4*col4..4*col4+3 of its tile: 8 coalesced float4
// loads, 16 sigmoid/softplus, one 32 B contiguous h4[4] store.
__global__ __launch_bounds__(512, 8) void sig_bce_kernel(
    const float* __restrict__ outputs,
    const float* __restrict__ targets,
    const float* __restrict__ level_w,
    h4*          __restrict__ Pg,
    float*       __restrict__ out)
{
    const int tid  = threadIdx.x;
    const int tile = blockIdx.x >> 1;               // 0..1023 (4 rows each)
    const int col4 = ((blockIdx.x & 1) << 9) + tid; // 0..1023 float4-col

    const float4* out4 = (const float4*)outputs;
    const float4* tgt4 = (const float4*)targets;
    const float4 w = ((const float4*)level_w)[col4];
    const float wv[4] = {w.x, w.y, w.z, w.w};

    float4 xs[4], ts[4];
#pragma unroll
    for (int r = 0; r < 4; ++r) {
        const size_t idx = (size_t)(4 * tile + r) * (N / 4) + col4;
        xs[r] = out4[idx];
        ts[r] = tgt4[idx];
    }

    float s1 = 0.0f;
    h4 tmp[4];                      // tmp[k][r] = p(row 4*tile+r, node 4*col4+k)
#pragma unroll
    for (int r = 0; r < 4; ++r) {
        const float xv[4] = {xs[r].x, xs[r].y, xs[r].z, xs[r].w};
        const float tv[4] = {ts[r].x, ts[r].y, ts[r].z, ts[r].w};
#pragma unroll
        for (int k = 0; k < 4; ++k) {
            float p, sp;
            fast_sig_sp(xv[k], p, sp);
            s1 = fmaf(wv[k], sp - xv[k] * tv[k], s1);
            tmp[k][r] = (_Float16)p;
        }
    }
    // 32 B contiguous store of 4 h4 slots (tile-major layout for K2's DMA)
    h8 lo = __builtin_shufflevector(tmp[0], tmp[1], 0, 1, 2, 3, 4, 5, 6, 7);
    h8 hi = __builtin_shufflevector(tmp[2], tmp[3], 0, 1, 2, 3, 4, 5, 6, 7);
    h8* dst = (h8*)&Pg[(size_t)tile * N + 4 * col4];
    dst[0] = lo;
    dst[1] = hi;

    // block reduce + one atomic
#pragma unroll
    for (int off = 32; off > 0; off >>= 1) s1 += __shfl_down(s1, off, 64);
    __shared__ float red[8];
    const int wave = tid >> 6, lane = tid & 63;
    if (lane == 0) red[wave] = s1;
    __syncthreads();
    if (tid == 0) {
        float a = 0.0f;
#pragma unroll
        for (int v = 0; v < 8; ++v) a += red[v];
        const float inv = 1.0f / ((float)B * (float)N);
        atomicAdd(out, ALPHA_C * a * inv);
    }
}

// ---------------- K2: DMA-staged edge gathers ----------------
// 256 blocks x 1024 threads; 4 tiles (16 rows) per block; double-buffered
// 32 KB LDS tiles filled by global_load_lds; vmcnt-only barriers.
__global__ __launch_bounds__(1024, 4) void edge_kernel(
    const h4* __restrict__ Pg,
    const int* __restrict__ edge_src,
    const int* __restrict__ edge_dst,
    float*     __restrict__ out)
{
    __shared__ h4 Pl[2][N];         // 2 x 32 KB

    const int tid = threadIdx.x;
    const int wv_ = tid >> 6;       // wave 0..15
    const int ln  = tid & 63;
    constexpr int EPT4 = E / 4 / 1024;   // 4 int4-chunks (16 edges)/thread

    const int4* es4 = (const int4*)edge_src;
    const int4* ed4 = (const int4*)edge_dst;

    // DMA one 32 KB tile into Pl[bufi]: per wave 2 x (64 lanes x 16 B) at
    // wave-uniform LDS base (the required global_load_lds dest pattern)
    auto copy_grp = [&](int t, int bufi) {
        const char* gbase = (const char*)&Pg[(size_t)t * N];
#pragma unroll
        for (int c = 0; c < 2; ++c) {
            const int boff = (c * 16 + wv_) * 1024;
            __builtin_amdgcn_global_load_lds(
                (const __attribute__((address_space(1))) void*)(gbase + boff + ln * 16),
                (__attribute__((address_space(3))) void*)((char*)&Pl[bufi][0] + boff),
                16, 0, 0);
        }
    };

    // edge indices into VGPRs (32 regs), issued before the first DMA
    int4 se[EPT4], de[EPT4];
#pragma unroll
    for (int j = 0; j < EPT4; ++j) {
        se[j] = es4[tid + j * 1024];
        de[j] = ed4[tid + j * 1024];
    }
    copy_grp(blockIdx.x * 4 + 0, 0);
    asm volatile("s_waitcnt vmcnt(0)" ::: "memory");   // idx + tile0 landed
    __builtin_amdgcn_s_barrier();

    float s2 = 0.0f;
#pragma unroll
    for (int k = 0; k < 4; ++k) {
        // issue next tile's DMA; it streams under this step's gathers
        if (k + 1 < 4) copy_grp(blockIdx.x * 4 + k + 1, (k + 1) & 1);
        __builtin_amdgcn_sched_barrier(0);

        const h4* Pc = Pl[k & 1];
        h4 acc0 = {0, 0, 0, 0};
        h4 acc1 = {0, 0, 0, 0};
        const h4 zero = {0, 0, 0, 0};
#pragma unroll
        for (int j = 0; j < EPT4; ++j) {
            const int4 s = se[j];
            const int4 d = de[j];
            h4 a0 = Pc[s.x], c0 = Pc[d.x];
            h4 a1 = Pc[s.y], c1 = Pc[d.y];
            h4 a2 = Pc[s.z], c2 = Pc[d.z];
            h4 a3 = Pc[s.w], c3 = Pc[d.w];
            acc0 += __builtin_elementwise_max(c0 - a0, zero);   // v_pk_* fp16
            acc1 += __builtin_elementwise_max(c1 - a1, zero);
            acc0 += __builtin_elementwise_max(c2 - a2, zero);
            acc1 += __builtin_elementwise_max(c3 - a3, zero);
        }
#pragma unroll
        for (int l = 0; l < 4; ++l) s2 += (float)acc0[l] + (float)acc1[l];

        if (k + 1 < 4) {
            // only the 2 in-flight DMA ops remain -> this wait is the
            // pipeline's counted sync point; no __syncthreads drain
            asm volatile("s_waitcnt vmcnt(0)" ::: "memory");
            __builtin_amdgcn_s_barrier();
        }
    }

    // block reduce + one atomic
#pragma unroll
    for (int off = 32; off > 0; off >>= 1) s2 += __shfl_down(s2, off, 64);
    __syncthreads();                 // all gathers done before LDS reuse
    float* red = (float*)Pl;
    if (ln == 0) red[wv_] = s2;
    __syncthreads();
    if (tid == 0) {
        float c = 0.0f;
#pragma unroll
        for (int v = 0; v < 16; ++v) c += red[v];
        const float inv = 1.0f / ((float)B * (float)N);
        atomicAdd(out, BETA_C * c * inv);
    }
}

// ---------------- fallback: proven R5 fused kernel ----------------
constexpr int FTHREADS = 512;
constexpr int FR = 4;

__global__ __launch_bounds__(FTHREADS, 8) void hier_loss_fallback(
    const float* __restrict__ outputs,
    const float* __restrict__ targets,
    const float* __restrict__ level_w,
    const int*   __restrict__ edge_src,
    const int*   __restrict__ edge_dst,
    float*       __restrict__ out)
{
    __shared__ h4 P[N];

    const int r0  = blockIdx.x * FR;
    const int tid = threadIdx.x;

    const float4* out4 = (const float4*)outputs;
    const float4* tgt4 = (const float4*)targets;
    const float4* lw4  = (const float4*)level_w;

    float s1 = 0.0f;
#pragma unroll
    for (int j = 0; j < N / 4 / FTHREADS; ++j) {
        const int n4 = tid + j * FTHREADS;
        const float4 w = lw4[n4];
        const float wv[4] = {w.x, w.y, w.z, w.w};
        float4 xs[FR], ts[FR];
#pragma unroll
        for (int r = 0; r < FR; ++r) {
            xs[r] = out4[(size_t)(r0 + r) * (N / 4) + n4];
            ts[r] = tgt4[(size_t)(r0 + r) * (N / 4) + n4];
        }
        h4 tmp[4];
#pragma unroll
        for (int r = 0; r < FR; ++r) {
            const float xv[4] = {xs[r].x, xs[r].y, xs[r].z, xs[r].w};
            const float tv[4] = {ts[r].x, ts[r].y, ts[r].z, ts[r].w};
#pragma unroll
            for (int k = 0; k < 4; ++k) {
                float p, sp;
                fast_sig_sp(xv[k], p, sp);
                s1 = fmaf(wv[k], sp - xv[k] * tv[k], s1);
                tmp[k][r] = (_Float16)p;
            }
        }
#pragma unroll
        for (int k = 0; k < 4; ++k) P[4 * n4 + k] = tmp[k];
    }
    __syncthreads();

    h4 acc0 = {0, 0, 0, 0};
    h4 acc1 = {0, 0, 0, 0};
    const h4 zero = {0, 0, 0, 0};
    const int4* es4 = (const int4*)edge_src;
    const int4* ed4 = (const int4*)edge_dst;
#pragma unroll
    for (int j = 0; j < E / 4 / FTHREADS; ++j) {
        const int i = tid + j * FTHREADS;
        const int4 s = es4[i];
        const int4 d = ed4[i];
        h4 a0 = P[s.x], c0 = P[d.x];
        h4 a1 = P[s.y], c1 = P[d.y];
        h4 a2 = P[s.z], c2 = P[d.z];
        h4 a3 = P[s.w], c3 = P[d.w];
        acc0 += __builtin_elementwise_max(c0 - a0, zero);
        acc1 += __builtin_elementwise_max(c1 - a1, zero);
        acc0 += __builtin_elementwise_max(c2 - a2, zero);
        acc1 += __builtin_elementwise_max(c3 - a3, zero);
    }
    float s2 = 0.0f;
#pragma unroll
    for (int l = 0; l < 4; ++l) s2 += (float)acc0[l] + (float)acc1[l];

#pragma unroll
    for (int off = 32; off > 0; off >>= 1) {
        s1 += __shfl_down(s1, off, 64);
        s2 += __shfl_down(s2, off, 64);
    }
    __syncthreads();
    float* red = (float*)P;
    const int wave = tid >> 6;
    const int lane = tid & 63;
    if (lane == 0) { red[wave] = s1; red[8 + wave] = s2; }
    __syncthreads();
    if (tid == 0) {
        float a = 0.0f, c = 0.0f;
#pragma unroll
        for (int w = 0; w < 8; ++w) { a += red[w]; c += red[8 + w]; }
        const float inv = 1.0f / ((float)B * (float)N);
        atomicAdd(out, (ALPHA_C * a + BETA_C * c) * inv);
    }
}

extern "C" void kernel_launch(void* const* d_in, const int* in_sizes, int n_in,
                              void* d_out, int out_size, void* d_ws, size_t ws_size,
                              hipStream_t stream) {
    const float* outputs = (const float*)d_in[0];
    const float* targets = (const float*)d_in[1];
    const float* level_w = (const float*)d_in[2];
    const int*   edge_src = (const int*)d_in[3];
    const int*   edge_dst = (const int*)d_in[4];
    float* out = (float*)d_out;

    init_out_kernel<<<1, 64, 0, stream>>>(out);
    if (ws_size >= PG_BYTES && d_ws != nullptr) {
        h4* Pg = (h4*)d_ws;
        sig_bce_kernel<<<2048, 512, 0, stream>>>(outputs, targets, level_w, Pg, out);
        edge_kernel<<<256, 1024, 0, stream>>>(Pg, edge_src, edge_dst, out);
    } else {
        hier_loss_fallback<<<B / FR, FTHREADS, 0, stream>>>(
            outputs, targets, level_w, edge_src, edge_dst, out);
    }
}

// Round 6
// 170.290 us; speedup vs baseline: 1.0058x; 1.0058x over previous
//
#include <hip/hip_runtime.h>
#include <math.h>

// loss = ALPHA * mean(level_w * (softplus(x) - x*t))
//      + BETA  * sum_{b,e} relu(sig(x[b,dst]) - sig(x[b,src])) / (B*N)
//
// R11: two-kernel split, atomics removed from the streaming path.
// R10 evidence: K1 (pure streaming, no barriers/gathers) ran at 60 us =
// 2.75 TB/s effective -- slower than the fused kernel. Suspects: (a) 2048
// same-address atomicAdds serialize at the LLC (~30 ns each ~= 60 us);
// (b) VGPR=28 proved the 8-deep load batch was never in flight. Fixes:
//  K1: no atomics at all -- per-tile BCE partial -> workspace; 1024 blocks
//      x 512 thr, 32 elements/thread, all 16 float4 loads batched under a
//      128-VGPR budget (__launch_bounds__(512,4)).
//  K2: unchanged DMA-staged gather pipeline (global_load_lds, double
//      buffer, vmcnt-only barriers) + folds 4 K1 partials into its one
//      atomic per block (256 atomics total, off the critical path).
// Fallback to the proven R5 fused kernel if workspace is too small.

#define ALPHA_C 1.0f
#define BETA_C  0.5f

constexpr int B = 4096;
constexpr int N = 4096;
constexpr int E = 16384;
constexpr int K1_BLOCKS = B / 4;                 // 1024 tiles of 4 rows
constexpr size_t PG_BYTES = (size_t)B * N * 2;   // 32 MB fp16 P
constexpr size_t WS_NEED = PG_BYTES + K1_BLOCKS * sizeof(float);

typedef _Float16 h4 __attribute__((ext_vector_type(4)));
typedef _Float16 h8 __attribute__((ext_vector_type(8)));

__global__ __launch_bounds__(64) void init_out_kernel(float* out) {
    if (threadIdx.x == 0) out[0] = 0.0f;
}

__device__ __forceinline__ void fast_sig_sp(float x, float& p, float& sp) {
    // q = exp(-|x|) in (0,1]; both sigmoid and softplus from one exp
    float q = __expf(-fabsf(x));
    float d = 1.0f + q;
    float r = __builtin_amdgcn_rcpf(d);     // ~1 ulp approx reciprocal
    p  = (x >= 0.0f) ? r : q * r;           // sigmoid
    sp = fmaxf(x, 0.0f) + __logf(d);        // softplus = max(x,0)+log(1+q)
}

// ---------------- K1: streaming sigmoid + BCE, P -> workspace ----------------
// 1024 blocks x 512 threads; block = tile (4 rows). Thread handles 2
// float4-columns (32 elements): all 16 x+t loads batched up front (16 KB
// per wave in flight), then transform, then 4x16B contiguous stores.
// BCE partial written to partials[tile] -- NO atomics in this kernel.
__global__ __launch_bounds__(512, 4) void sig_bce_kernel(
    const float* __restrict__ outputs,
    const float* __restrict__ targets,
    const float* __restrict__ level_w,
    h4*          __restrict__ Pg,
    float*       __restrict__ partials)
{
    const int tid  = threadIdx.x;
    const int tile = blockIdx.x;                 // 0..1023

    const float4* out4 = (const float4*)outputs;
    const float4* tgt4 = (const float4*)targets;
    const float4* lw4  = (const float4*)level_w;

    // batch ALL loads first: 2 lw + 16 x/t float4 loads in flight
    float4 w[2], xs[2][4], ts[2][4];
#pragma unroll
    for (int c = 0; c < 2; ++c) {
        const int col4 = tid + c * 512;
        w[c] = lw4[col4];
#pragma unroll
        for (int r = 0; r < 4; ++r) {
            const size_t idx = (size_t)(4 * tile + r) * (N / 4) + col4;
            xs[c][r] = out4[idx];
            ts[c][r] = tgt4[idx];
        }
    }
    __builtin_amdgcn_sched_barrier(0);           // keep the batch issued

    float s1 = 0.0f;
#pragma unroll
    for (int c = 0; c < 2; ++c) {
        const int col4 = tid + c * 512;
        const float wv[4] = {w[c].x, w[c].y, w[c].z, w[c].w};
        h4 tmp[4];                  // tmp[k][r] = p(row 4*tile+r, node 4*col4+k)
#pragma unroll
        for (int r = 0; r < 4; ++r) {
            const float xv[4] = {xs[c][r].x, xs[c][r].y, xs[c][r].z, xs[c][r].w};
            const float tv[4] = {ts[c][r].x, ts[c][r].y, ts[c][r].z, ts[c][r].w};
#pragma unroll
            for (int k = 0; k < 4; ++k) {
                float p, sp;
                fast_sig_sp(xv[k], p, sp);
                s1 = fmaf(wv[k], sp - xv[k] * tv[k], s1);
                tmp[k][r] = (_Float16)p;
            }
        }
        // 32 B contiguous store of 4 h4 slots (tile-major layout for K2 DMA)
        h8 lo = __builtin_shufflevector(tmp[0], tmp[1], 0, 1, 2, 3, 4, 5, 6, 7);
        h8 hi = __builtin_shufflevector(tmp[2], tmp[3], 0, 1, 2, 3, 4, 5, 6, 7);
        h8* dst = (h8*)&Pg[(size_t)tile * N + 4 * col4];
        dst[0] = lo;
        dst[1] = hi;
    }

    // block reduce -> plain store (no atomic)
#pragma unroll
    for (int off = 32; off > 0; off >>= 1) s1 += __shfl_down(s1, off, 64);
    __shared__ float red[8];
    const int wave = tid >> 6, lane = tid & 63;
    if (lane == 0) red[wave] = s1;
    __syncthreads();
    if (tid == 0) {
        float a = 0.0f;
#pragma unroll
        for (int v = 0; v < 8; ++v) a += red[v];
        partials[tile] = a;
    }
}

// ---------------- K2: DMA-staged edge gathers + partial fold ----------------
// 256 blocks x 1024 threads; 4 tiles (16 rows) per block; double-buffered
// 32 KB LDS tiles filled by global_load_lds; vmcnt-only barriers.
__global__ __launch_bounds__(1024, 4) void edge_kernel(
    const h4* __restrict__ Pg,
    const int* __restrict__ edge_src,
    const int* __restrict__ edge_dst,
    const float* __restrict__ partials,
    float*     __restrict__ out)
{
    __shared__ h4 Pl[2][N];         // 2 x 32 KB

    const int tid = threadIdx.x;
    const int wv_ = tid >> 6;       // wave 0..15
    const int ln  = tid & 63;
    constexpr int EPT4 = E / 4 / 1024;   // 4 int4-chunks (16 edges)/thread

    const int4* es4 = (const int4*)edge_src;
    const int4* ed4 = (const int4*)edge_dst;

    // DMA one 32 KB tile into Pl[bufi]: per wave 2 x (64 lanes x 16 B) at
    // wave-uniform LDS base (the required global_load_lds dest pattern)
    auto copy_grp = [&](int t, int bufi) {
        const char* gbase = (const char*)&Pg[(size_t)t * N];
#pragma unroll
        for (int c = 0; c < 2; ++c) {
            const int boff = (c * 16 + wv_) * 1024;
            __builtin_amdgcn_global_load_lds(
                (const __attribute__((address_space(1))) void*)(gbase + boff + ln * 16),
                (__attribute__((address_space(3))) void*)((char*)&Pl[bufi][0] + boff),
                16, 0, 0);
        }
    };

    // edge indices into VGPRs (32 regs), issued before the first DMA
    int4 se[EPT4], de[EPT4];
#pragma unroll
    for (int j = 0; j < EPT4; ++j) {
        se[j] = es4[tid + j * 1024];
        de[j] = ed4[tid + j * 1024];
    }
    copy_grp(blockIdx.x * 4 + 0, 0);
    asm volatile("s_waitcnt vmcnt(0)" ::: "memory");   // idx + tile0 landed
    __builtin_amdgcn_s_barrier();

    float s2 = 0.0f;
#pragma unroll
    for (int k = 0; k < 4; ++k) {
        // issue next tile's DMA; it streams under this step's gathers
        if (k + 1 < 4) copy_grp(blockIdx.x * 4 + k + 1, (k + 1) & 1);
        __builtin_amdgcn_sched_barrier(0);

        const h4* Pc = Pl[k & 1];
        h4 acc0 = {0, 0, 0, 0};
        h4 acc1 = {0, 0, 0, 0};
        const h4 zero = {0, 0, 0, 0};
#pragma unroll
        for (int j = 0; j < EPT4; ++j) {
            const int4 s = se[j];
            const int4 d = de[j];
            h4 a0 = Pc[s.x], c0 = Pc[d.x];
            h4 a1 = Pc[s.y], c1 = Pc[d.y];
            h4 a2 = Pc[s.z], c2 = Pc[d.z];
            h4 a3 = Pc[s.w], c3 = Pc[d.w];
            acc0 += __builtin_elementwise_max(c0 - a0, zero);   // v_pk_* fp16
            acc1 += __builtin_elementwise_max(c1 - a1, zero);
            acc0 += __builtin_elementwise_max(c2 - a2, zero);
            acc1 += __builtin_elementwise_max(c3 - a3, zero);
        }
#pragma unroll
        for (int l = 0; l < 4; ++l) s2 += (float)acc0[l] + (float)acc1[l];

        if (k + 1 < 4) {
            // only the in-flight DMA ops remain -> counted sync point;
            // no __syncthreads vmcnt-drain convoy
            asm volatile("s_waitcnt vmcnt(0)" ::: "memory");
            __builtin_amdgcn_s_barrier();
        }
    }

    // block reduce + one atomic (256 total), folding 4 K1 partials
#pragma unroll
    for (int off = 32; off > 0; off >>= 1) s2 += __shfl_down(s2, off, 64);
    __syncthreads();                 // all gathers done before LDS reuse
    float* red = (float*)Pl;
    if (ln == 0) red[wv_] = s2;
    __syncthreads();
    if (tid == 0) {
        float c = 0.0f;
#pragma unroll
        for (int v = 0; v < 16; ++v) c += red[v];
        const float4 pp = ((const float4*)partials)[blockIdx.x];
        const float a = pp.x + pp.y + pp.z + pp.w;
        const float inv = 1.0f / ((float)B * (float)N);
        atomicAdd(out, (ALPHA_C * a + BETA_C * c) * inv);
    }
}

// ---------------- fallback: proven R5 fused kernel ----------------
constexpr int FTHREADS = 512;
constexpr int FR = 4;

__global__ __launch_bounds__(FTHREADS, 8) void hier_loss_fallback(
    const float* __restrict__ outputs,
    const float* __restrict__ targets,
    const float* __restrict__ level_w,
    const int*   __restrict__ edge_src,
    const int*   __restrict__ edge_dst,
    float*       __restrict__ out)
{
    __shared__ h4 P[N];

    const int r0  = blockIdx.x * FR;
    const int tid = threadIdx.x;

    const float4* out4 = (const float4*)outputs;
    const float4* tgt4 = (const float4*)targets;
    const float4* lw4  = (const float4*)level_w;

    float s1 = 0.0f;
#pragma unroll
    for (int j = 0; j < N / 4 / FTHREADS; ++j) {
        const int n4 = tid + j * FTHREADS;
        const float4 w = lw4[n4];
        const float wv[4] = {w.x, w.y, w.z, w.w};
        float4 xs[FR], ts[FR];
#pragma unroll
        for (int r = 0; r < FR; ++r) {
            xs[r] = out4[(size_t)(r0 + r) * (N / 4) + n4];
            ts[r] = tgt4[(size_t)(r0 + r) * (N / 4) + n4];
        }
        h4 tmp[4];
#pragma unroll
        for (int r = 0; r < FR; ++r) {
            const float xv[4] = {xs[r].x, xs[r].y, xs[r].z, xs[r].w};
            const float tv[4] = {ts[r].x, ts[r].y, ts[r].z, ts[r].w};
#pragma unroll
            for (int k = 0; k < 4; ++k) {
                float p, sp;
                fast_sig_sp(xv[k], p, sp);
                s1 = fmaf(wv[k], sp - xv[k] * tv[k], s1);
                tmp[k][r] = (_Float16)p;
            }
        }
#pragma unroll
        for (int k = 0; k < 4; ++k) P[4 * n4 + k] = tmp[k];
    }
    __syncthreads();

    h4 acc0 = {0, 0, 0, 0};
    h4 acc1 = {0, 0, 0, 0};
    const h4 zero = {0, 0, 0, 0};
    const int4* es4 = (const int4*)edge_src;
    const int4* ed4 = (const int4*)edge_dst;
#pragma unroll
    for (int j = 0; j < E / 4 / FTHREADS; ++j) {
        const int i = tid + j * FTHREADS;
        const int4 s = es4[i];
        const int4 d = ed4[i];
        h4 a0 = P[s.x], c0 = P[d.x];
        h4 a1 = P[s.y], c1 = P[d.y];
        h4 a2 = P[s.z], c2 = P[d.z];
        h4 a3 = P[s.w], c3 = P[d.w];
        acc0 += __builtin_elementwise_max(c0 - a0, zero);
        acc1 += __builtin_elementwise_max(c1 - a1, zero);
        acc0 += __builtin_elementwise_max(c2 - a2, zero);
        acc1 += __builtin_elementwise_max(c3 - a3, zero);
    }
    float s2 = 0.0f;
#pragma unroll
    for (int l = 0; l < 4; ++l) s2 += (float)acc0[l] + (float)acc1[l];

#pragma unroll
    for (int off = 32; off > 0; off >>= 1) {
        s1 += __shfl_down(s1, off, 64);
        s2 += __shfl_down(s2, off, 64);
    }
    __syncthreads();
    float* red = (float*)P;
    const int wave = tid >> 6;
    const int lane = tid & 63;
    if (lane == 0) { red[wave] = s1; red[8 + wave] = s2; }
    __syncthreads();
    if (tid == 0) {
        float a = 0.0f, c = 0.0f;
#pragma unroll
        for (int w = 0; w < 8; ++w) { a += red[w]; c += red[8 + w]; }
        const float inv = 1.0f / ((float)B * (float)N);
        atomicAdd(out, (ALPHA_C * a + BETA_C * c) * inv);
    }
}

extern "C" void kernel_launch(void* const* d_in, const int* in_sizes, int n_in,
                              void* d_out, int out_size, void* d_ws, size_t ws_size,
                              hipStream_t stream) {
    const float* outputs = (const float*)d_in[0];
    const float* targets = (const float*)d_in[1];
    const float* level_w = (const float*)d_in[2];
    const int*   edge_src = (const int*)d_in[3];
    const int*   edge_dst = (const int*)d_in[4];
    float* out = (float*)d_out;

    init_out_kernel<<<1, 64, 0, stream>>>(out);
    if (ws_size >= WS_NEED && d_ws != nullptr) {
        h4*    Pg       = (h4*)d_ws;
        float* partials = (float*)((char*)d_ws + PG_BYTES);
        sig_bce_kernel<<<K1_BLOCKS, 512, 0, stream>>>(outputs, targets, level_w,
                                                      Pg, partials);
        edge_kernel<<<256, 1024, 0, stream>>>(Pg, edge_src, edge_dst,
                                              partials, out);
    } else {
        hier_loss_fallback<<<B / FR, FTHREADS, 0, stream>>>(
            outputs, targets, level_w, edge_src, edge_dst, out);
    }
}